// Round 1
// baseline (1033.750 us; speedup 1.0000x reference)
//
#include <hip/hip_runtime.h>
#include <hip/hip_bf16.h>
#include <stdint.h>

#define B_ 4
#define C_ 16
#define P_ 512
#define D_ 256
#define H_ 8
#define SCALE 0.17677669529663687f  // 1/sqrt(32)

typedef float4 f4;

__device__ __forceinline__ float bf16lo(uint32_t w) { return __uint_as_float(w << 16); }
__device__ __forceinline__ float bf16hi(uint32_t w) { return __uint_as_float(w & 0xffff0000u); }

// ---------------- projection: QU = qz @ U^T, QV = qz @ V^T (per batch) ----------------
// grid (D/64, 8192/128, B), block 256. Tile 128m x 64n, K-step 8. Both outputs share A tile.
__global__ __launch_bounds__(256)
void proj_kernel(const float* __restrict__ qz, const float* __restrict__ U,
                 const float* __restrict__ V, float* __restrict__ qu,
                 float* __restrict__ qv) {
  const int b = blockIdx.z;
  const int m0 = blockIdx.y * 128;
  const int n0 = blockIdx.x * 64;
  const float* A  = qz + (size_t)b * ((size_t)C_ * P_ * D_);
  const float* Ub = U  + (size_t)b * D_ * D_;
  const float* Vb = V  + (size_t)b * D_ * D_;

  __shared__ float As[8][128];
  __shared__ float Us[8][64];
  __shared__ float Vs[8][64];

  const int tid = threadIdx.x;
  const int tm = (tid >> 4) * 8;   // 8 rows per thread
  const int tn = (tid & 15) * 4;   // 4 cols per thread
  const int lr = tid >> 1;         // A-load row
  const int lk = (tid & 1) * 4;    // A-load k
  const int wn = tid >> 2;         // W-load row
  const int wk = (tid & 3) * 2;    // W-load k

  float accU[8][4] = {{0.f}};
  float accV[8][4] = {{0.f}};

  for (int kt = 0; kt < D_; kt += 8) {
    f4 av = *(const f4*)&A[(size_t)(m0 + lr) * D_ + kt + lk];
    As[lk+0][lr] = av.x; As[lk+1][lr] = av.y; As[lk+2][lr] = av.z; As[lk+3][lr] = av.w;
    float2 u2 = *(const float2*)&Ub[(size_t)(n0 + wn) * D_ + kt + wk];
    Us[wk+0][wn] = u2.x; Us[wk+1][wn] = u2.y;
    float2 v2 = *(const float2*)&Vb[(size_t)(n0 + wn) * D_ + kt + wk];
    Vs[wk+0][wn] = v2.x; Vs[wk+1][wn] = v2.y;
    __syncthreads();
#pragma unroll
    for (int k = 0; k < 8; ++k) {
      f4 a0 = *(const f4*)&As[k][tm];
      f4 a1 = *(const f4*)&As[k][tm+4];
      f4 u4 = *(const f4*)&Us[k][tn];
      f4 v4 = *(const f4*)&Vs[k][tn];
      float ar[8] = {a0.x,a0.y,a0.z,a0.w,a1.x,a1.y,a1.z,a1.w};
      float uu[4] = {u4.x,u4.y,u4.z,u4.w};
      float vv[4] = {v4.x,v4.y,v4.z,v4.w};
#pragma unroll
      for (int i = 0; i < 8; ++i)
#pragma unroll
        for (int j = 0; j < 4; ++j) {
          accU[i][j] = fmaf(ar[i], uu[j], accU[i][j]);
          accV[i][j] = fmaf(ar[i], vv[j], accV[i][j]);
        }
    }
    __syncthreads();
  }
#pragma unroll
  for (int i = 0; i < 8; ++i) {
    size_t off = ((size_t)b * 8192 + m0 + tm + i) * D_ + n0 + tn;
    *(f4*)&qu[off] = make_float4(accU[i][0], accU[i][1], accU[i][2], accU[i][3]);
    *(f4*)&qv[off] = make_float4(accV[i][0], accV[i][1], accV[i][2], accV[i][3]);
  }
}

// ---------------- fused time attention ----------------
// grid (P/32, C, B), block 256 (4 waves). Per block: 32 query rows.
// loop h: QK (regs) -> wave softmax -> acc += attn/8 (regs). Then A->LDS bf16, PV.
__global__ __launch_bounds__(256)
void time_attn_kernel(const float* __restrict__ qu, const float* __restrict__ qv,
                      const float* __restrict__ qz, float* __restrict__ out) {
  const int b = blockIdx.z, c = blockIdx.y, pt = blockIdx.x;
  const int row0 = pt * 32;
  const size_t base = ((size_t)b * C_ + c) * (size_t)P_ * D_;

  __shared__ float quS[32][36];
  __shared__ float smem[9216];               // qvS[key][36] (key<256) or qzS[k][264] (k<32)
  __shared__ __align__(16) __hip_bfloat16 A_s[32][512];

  const int tid = threadIdx.x;
  const int rg = tid >> 6;                   // wave id 0..3 -> rows rg*8..+7
  const int cg = tid & 63;                   // lane
  const int ldr = tid >> 3;                  // 0..31 (loader row)
  const int ldk = (tid & 7) * 4;             // loader k offset

  float acc[8][8];
#pragma unroll
  for (int i = 0; i < 8; ++i)
#pragma unroll
    for (int j = 0; j < 8; ++j) acc[i][j] = 0.f;

  for (int h = 0; h < H_; ++h) {
    {
      f4 t = *(const f4*)&qu[base + (size_t)(row0 + ldr) * D_ + h*32 + ldk];
      quS[ldr][ldk+0]=t.x; quS[ldr][ldk+1]=t.y; quS[ldr][ldk+2]=t.z; quS[ldr][ldk+3]=t.w;
    }
    float s[8][8];
#pragma unroll
    for (int i = 0; i < 8; ++i)
#pragma unroll
      for (int j = 0; j < 8; ++j) s[i][j] = 0.f;

    for (int hf = 0; hf < 2; ++hf) {
#pragma unroll
      for (int jj = 0; jj < 8; ++jj) {
        int key = jj*32 + ldr;
        f4 t = *(const f4*)&qv[base + (size_t)(hf*256 + key) * D_ + h*32 + ldk];
        float* dst = &smem[key*36 + ldk];
        dst[0]=t.x; dst[1]=t.y; dst[2]=t.z; dst[3]=t.w;
      }
      __syncthreads();
#pragma unroll
      for (int k4 = 0; k4 < 8; ++k4) {
        f4 a[8];
#pragma unroll
        for (int ri = 0; ri < 8; ++ri) a[ri] = *(const f4*)&quS[rg*8+ri][k4*4];
#pragma unroll
        for (int cj = 0; cj < 4; ++cj) {
          f4 v = *(const f4*)&smem[(cj*64+cg)*36 + k4*4];
#pragma unroll
          for (int ri = 0; ri < 8; ++ri)
            s[ri][hf*4+cj] += a[ri].x*v.x + a[ri].y*v.y + a[ri].z*v.z + a[ri].w*v.w;
        }
      }
      __syncthreads();
    }
    // softmax per row across the wave (row r = rg*8+ri is fully owned by wave rg)
#pragma unroll
    for (int ri = 0; ri < 8; ++ri) {
      float mx = s[ri][0];
#pragma unroll
      for (int j = 1; j < 8; ++j) mx = fmaxf(mx, s[ri][j]);
      for (int off = 32; off >= 1; off >>= 1) mx = fmaxf(mx, __shfl_xor(mx, off));
      float p[8];
      float sum = 0.f;
#pragma unroll
      for (int j = 0; j < 8; ++j) { p[j] = __expf((s[ri][j] - mx) * SCALE); sum += p[j]; }
      for (int off = 32; off >= 1; off >>= 1) sum += __shfl_xor(sum, off);
      float w = 0.125f / sum;
#pragma unroll
      for (int j = 0; j < 8; ++j) acc[ri][j] += p[j] * w;
    }
  }
  // head-mean attention -> LDS (bf16)
#pragma unroll
  for (int ri = 0; ri < 8; ++ri)
#pragma unroll
    for (int hf = 0; hf < 2; ++hf)
#pragma unroll
      for (int cj = 0; cj < 4; ++cj)
        A_s[rg*8+ri][hf*256 + cj*64 + cg] = __float2bfloat16(acc[ri][hf*4+cj]);
  __syncthreads();

  // PV: (32 x 512) @ (512 x 256)
  float acco[8][4];
#pragma unroll
  for (int i = 0; i < 8; ++i)
#pragma unroll
    for (int j = 0; j < 4; ++j) acco[i][j] = 0.f;

  for (int kc = 0; kc < 16; ++kc) {
#pragma unroll
    for (int dd = 0; dd < 8; ++dd) {
      int d = (tid & 7) * 4 + dd * 32;
      f4 t = *(const f4*)&qz[base + (size_t)(kc*32 + ldr) * D_ + d];
      float* dst = &smem[ldr*264 + d];
      dst[0]=t.x; dst[1]=t.y; dst[2]=t.z; dst[3]=t.w;
    }
    __syncthreads();
#pragma unroll
    for (int k8 = 0; k8 < 4; ++k8) {
      uint4 aw[8];
#pragma unroll
      for (int ri = 0; ri < 8; ++ri)
        aw[ri] = *(const uint4*)&A_s[rg*8+ri][kc*32 + k8*8];
#pragma unroll
      for (int kk = 0; kk < 8; ++kk) {
        float z[4];
#pragma unroll
        for (int cj = 0; cj < 4; ++cj) z[cj] = smem[(k8*8+kk)*264 + cj*64 + cg];
#pragma unroll
        for (int ri = 0; ri < 8; ++ri) {
          uint32_t wds[4] = {aw[ri].x, aw[ri].y, aw[ri].z, aw[ri].w};
          uint32_t wd = wds[kk >> 1];
          float a = (kk & 1) ? bf16hi(wd) : bf16lo(wd);
#pragma unroll
          for (int cj = 0; cj < 4; ++cj) acco[ri][cj] = fmaf(a, z[cj], acco[ri][cj]);
        }
      }
    }
    __syncthreads();
  }
#pragma unroll
  for (int ri = 0; ri < 8; ++ri)
#pragma unroll
    for (int cj = 0; cj < 4; ++cj)
      out[base + (size_t)(row0 + rg*8 + ri) * D_ + cj*64 + cg] = acco[ri][cj];
}

// ---------------- fused channel attention ----------------
// grid (P, B), block 64 (1 wave). Per block: one p, all 16 channels, 8 heads.
__global__ __launch_bounds__(64)
void chan_attn_kernel(const float* __restrict__ qu, const float* __restrict__ qv,
                      const float* __restrict__ qz, float* __restrict__ out) {
  const int p = blockIdx.x, b = blockIdx.y;
  __shared__ float buf0[16][260];   // quC during logits, qzC during PV
  __shared__ float qvC[16][260];
  __shared__ float A_m[16][17];

  const int tid = threadIdx.x;   // 0..63
  const int f = tid & 15;
  const int g = tid >> 4;        // 0..3

#pragma unroll
  for (int cc = 0; cc < 16; ++cc) {
    size_t off = (((size_t)b * C_ + cc) * P_ + p) * D_ + tid*4;
    *(f4*)&buf0[cc][tid*4] = *(const f4*)&qu[off];
    *(f4*)&qvC[cc][tid*4]  = *(const f4*)&qv[off];
  }
  __syncthreads();

  float am[4] = {0.f, 0.f, 0.f, 0.f};
  for (int h = 0; h < H_; ++h) {
    f4 vr[8];
#pragma unroll
    for (int i = 0; i < 8; ++i) vr[i] = *(const f4*)&qvC[f][h*32 + i*4];
    float sj[4];
#pragma unroll
    for (int j = 0; j < 4; ++j) {
      int cc = g + 4*j;
      float ssum = 0.f;
#pragma unroll
      for (int i = 0; i < 8; ++i) {
        f4 uu = *(const f4*)&buf0[cc][h*32 + i*4];
        ssum += uu.x*vr[i].x + uu.y*vr[i].y + uu.z*vr[i].z + uu.w*vr[i].w;
      }
      sj[j] = ssum;
    }
#pragma unroll
    for (int j = 0; j < 4; ++j) {
      float mx = sj[j];
      for (int off = 8; off >= 1; off >>= 1) mx = fmaxf(mx, __shfl_xor(mx, off));
      float pv = __expf((sj[j] - mx) * SCALE);
      float sum = pv;
      for (int off = 8; off >= 1; off >>= 1) sum += __shfl_xor(sum, off);
      am[j] += pv * (0.125f / sum);
    }
  }
#pragma unroll
  for (int j = 0; j < 4; ++j) A_m[g + 4*j][f] = am[j];
  __syncthreads();
  // reload buf0 with qz rows (channel index is the row here: qzp[b,p,f,:] = qz[b,f,p,:])
#pragma unroll
  for (int cc = 0; cc < 16; ++cc) {
    size_t off = (((size_t)b * C_ + cc) * P_ + p) * D_ + tid*4;
    *(f4*)&buf0[cc][tid*4] = *(const f4*)&qz[off];
  }
  __syncthreads();

  f4 acc4[16];
#pragma unroll
  for (int cc = 0; cc < 16; ++cc) acc4[cc] = make_float4(0.f, 0.f, 0.f, 0.f);
#pragma unroll
  for (int ff = 0; ff < 16; ++ff) {
    f4 z = *(const f4*)&buf0[ff][tid*4];
#pragma unroll
    for (int cc = 0; cc < 16; ++cc) {
      float aa = A_m[cc][ff];
      acc4[cc].x = fmaf(aa, z.x, acc4[cc].x);
      acc4[cc].y = fmaf(aa, z.y, acc4[cc].y);
      acc4[cc].z = fmaf(aa, z.z, acc4[cc].z);
      acc4[cc].w = fmaf(aa, z.w, acc4[cc].w);
    }
  }
#pragma unroll
  for (int cc = 0; cc < 16; ++cc) {
    size_t off = (((size_t)b * C_ + cc) * P_ + p) * D_ + tid*4;
    *(f4*)&out[off] = acc4[cc];
  }
}

extern "C" void kernel_launch(void* const* d_in, const int* in_sizes, int n_in,
                              void* d_out, int out_size, void* d_ws, size_t ws_size,
                              hipStream_t stream) {
  const float* qz = (const float*)d_in[0];
  const float* tu = (const float*)d_in[1];
  const float* tv = (const float*)d_in[2];
  const float* cu = (const float*)d_in[3];
  const float* cv = (const float*)d_in[4];
  float* out_mt = (float*)d_out;
  float* out_mc = out_mt + (size_t)B_ * C_ * P_ * D_;
  float* quW = (float*)d_ws;                              // 33.55 MB
  float* qvW = quW + (size_t)B_ * C_ * P_ * D_;           // 33.55 MB (ws total 67.1 MB)

  dim3 pg(D_/64, (C_*P_)/128, B_);
  hipLaunchKernelGGL(proj_kernel, pg, dim3(256), 0, stream, qz, tu, tv, quW, qvW);
  hipLaunchKernelGGL(time_attn_kernel, dim3(P_/32, C_, B_), dim3(256), 0, stream,
                     quW, qvW, qz, out_mt);
  hipLaunchKernelGGL(proj_kernel, pg, dim3(256), 0, stream, qz, cu, cv, quW, qvW);
  hipLaunchKernelGGL(chan_attn_kernel, dim3(P_, B_), dim3(64), 0, stream,
                     quW, qvW, qz, out_mc);
}

// Round 2
// 441.307 us; speedup vs baseline: 2.3425x; 2.3425x over previous
//
#include <hip/hip_runtime.h>
#include <hip/hip_bf16.h>
#include <stdint.h>

#define B_ 4
#define C_ 16
#define P_ 512
#define D_ 256
#define H_ 8
#define SCALE 0.17677669529663687f  // 1/sqrt(32)

typedef float4 f4;
typedef uint32_t u32;
typedef __attribute__((ext_vector_type(4))) float f32x4;
typedef __attribute__((ext_vector_type(8))) short short8;
typedef __attribute__((ext_vector_type(4))) short s16x4;

__device__ __forceinline__ unsigned short bf16bits(float x) {
  union { __hip_bfloat16 h; unsigned short u; } cv;
  cv.h = __float2bfloat16(x);
  return cv.u;
}

// ---------------- projection (fp32 out, for channel branch) ----------------
__global__ __launch_bounds__(256)
void proj_kernel(const float* __restrict__ qz, const float* __restrict__ U,
                 const float* __restrict__ V, float* __restrict__ qu,
                 float* __restrict__ qv) {
  const int b = blockIdx.z;
  const int m0 = blockIdx.y * 128;
  const int n0 = blockIdx.x * 64;
  const float* A  = qz + (size_t)b * ((size_t)C_ * P_ * D_);
  const float* Ub = U  + (size_t)b * D_ * D_;
  const float* Vb = V  + (size_t)b * D_ * D_;

  __shared__ float As[8][128];
  __shared__ float Us[8][64];
  __shared__ float Vs[8][64];

  const int tid = threadIdx.x;
  const int tm = (tid >> 4) * 8;
  const int tn = (tid & 15) * 4;
  const int lr = tid >> 1;
  const int lk = (tid & 1) * 4;
  const int wn = tid >> 2;
  const int wk = (tid & 3) * 2;

  float accU[8][4] = {{0.f}};
  float accV[8][4] = {{0.f}};

  for (int kt = 0; kt < D_; kt += 8) {
    f4 av = *(const f4*)&A[(size_t)(m0 + lr) * D_ + kt + lk];
    As[lk+0][lr] = av.x; As[lk+1][lr] = av.y; As[lk+2][lr] = av.z; As[lk+3][lr] = av.w;
    float2 u2 = *(const float2*)&Ub[(size_t)(n0 + wn) * D_ + kt + wk];
    Us[wk+0][wn] = u2.x; Us[wk+1][wn] = u2.y;
    float2 v2 = *(const float2*)&Vb[(size_t)(n0 + wn) * D_ + kt + wk];
    Vs[wk+0][wn] = v2.x; Vs[wk+1][wn] = v2.y;
    __syncthreads();
#pragma unroll
    for (int k = 0; k < 8; ++k) {
      f4 a0 = *(const f4*)&As[k][tm];
      f4 a1 = *(const f4*)&As[k][tm+4];
      f4 u4 = *(const f4*)&Us[k][tn];
      f4 v4 = *(const f4*)&Vs[k][tn];
      float ar[8] = {a0.x,a0.y,a0.z,a0.w,a1.x,a1.y,a1.z,a1.w};
      float uu[4] = {u4.x,u4.y,u4.z,u4.w};
      float vv[4] = {v4.x,v4.y,v4.z,v4.w};
#pragma unroll
      for (int i = 0; i < 8; ++i)
#pragma unroll
        for (int j = 0; j < 4; ++j) {
          accU[i][j] = fmaf(ar[i], uu[j], accU[i][j]);
          accV[i][j] = fmaf(ar[i], vv[j], accV[i][j]);
        }
    }
    __syncthreads();
  }
#pragma unroll
  for (int i = 0; i < 8; ++i) {
    size_t off = ((size_t)b * 8192 + m0 + tm + i) * D_ + n0 + tn;
    *(f4*)&qu[off] = make_float4(accU[i][0], accU[i][1], accU[i][2], accU[i][3]);
    *(f4*)&qv[off] = make_float4(accV[i][0], accV[i][1], accV[i][2], accV[i][3]);
  }
}

// ---------------- projection (bf16 hi/lo split out, per-head layout) ----------------
// writes quh/qul/qvh/qvl as [b][c][h][p][32] bf16
__global__ __launch_bounds__(256)
void proj_time_kernel(const float* __restrict__ qz, const float* __restrict__ U,
                      const float* __restrict__ V,
                      __hip_bfloat16* __restrict__ quh, __hip_bfloat16* __restrict__ qul,
                      __hip_bfloat16* __restrict__ qvh, __hip_bfloat16* __restrict__ qvl) {
  const int b = blockIdx.z;
  const int m0 = blockIdx.y * 128;
  const int n0 = blockIdx.x * 64;
  const float* A  = qz + (size_t)b * ((size_t)C_ * P_ * D_);
  const float* Ub = U  + (size_t)b * D_ * D_;
  const float* Vb = V  + (size_t)b * D_ * D_;

  __shared__ float As[8][128];
  __shared__ float Us[8][64];
  __shared__ float Vs[8][64];

  const int tid = threadIdx.x;
  const int tm = (tid >> 4) * 8;
  const int tn = (tid & 15) * 4;
  const int lr = tid >> 1;
  const int lk = (tid & 1) * 4;
  const int wn = tid >> 2;
  const int wk = (tid & 3) * 2;

  float accU[8][4] = {{0.f}};
  float accV[8][4] = {{0.f}};

  for (int kt = 0; kt < D_; kt += 8) {
    f4 av = *(const f4*)&A[(size_t)(m0 + lr) * D_ + kt + lk];
    As[lk+0][lr] = av.x; As[lk+1][lr] = av.y; As[lk+2][lr] = av.z; As[lk+3][lr] = av.w;
    float2 u2 = *(const float2*)&Ub[(size_t)(n0 + wn) * D_ + kt + wk];
    Us[wk+0][wn] = u2.x; Us[wk+1][wn] = u2.y;
    float2 v2 = *(const float2*)&Vb[(size_t)(n0 + wn) * D_ + kt + wk];
    Vs[wk+0][wn] = v2.x; Vs[wk+1][wn] = v2.y;
    __syncthreads();
#pragma unroll
    for (int k = 0; k < 8; ++k) {
      f4 a0 = *(const f4*)&As[k][tm];
      f4 a1 = *(const f4*)&As[k][tm+4];
      f4 u4 = *(const f4*)&Us[k][tn];
      f4 v4 = *(const f4*)&Vs[k][tn];
      float ar[8] = {a0.x,a0.y,a0.z,a0.w,a1.x,a1.y,a1.z,a1.w};
      float uu[4] = {u4.x,u4.y,u4.z,u4.w};
      float vv[4] = {v4.x,v4.y,v4.z,v4.w};
#pragma unroll
      for (int i = 0; i < 8; ++i)
#pragma unroll
        for (int j = 0; j < 4; ++j) {
          accU[i][j] = fmaf(ar[i], uu[j], accU[i][j]);
          accV[i][j] = fmaf(ar[i], vv[j], accV[i][j]);
        }
    }
    __syncthreads();
  }
  const int n = n0 + tn;
  const int h = n >> 5;
  const int r = n & 31;
#pragma unroll
  for (int i = 0; i < 8; ++i) {
    int m = m0 + tm + i;
    int cc = m >> 9;
    int p = m & 511;
    size_t dst = ((((size_t)b * C_ + cc) * H_ + h) * P_ + p) * 32 + r;
    unsigned short uh[4], ul[4], vh[4], vl[4];
#pragma unroll
    for (int j = 0; j < 4; ++j) {
      float x = accU[i][j];
      unsigned short hb = bf16bits(x);
      uh[j] = hb;
      ul[j] = bf16bits(x - __uint_as_float((u32)hb << 16));
      float y = accV[i][j];
      unsigned short hb2 = bf16bits(y);
      vh[j] = hb2;
      vl[j] = bf16bits(y - __uint_as_float((u32)hb2 << 16));
    }
    *(ushort4*)(quh + dst) = make_ushort4(uh[0], uh[1], uh[2], uh[3]);
    *(ushort4*)(qul + dst) = make_ushort4(ul[0], ul[1], ul[2], ul[3]);
    *(ushort4*)(qvh + dst) = make_ushort4(vh[0], vh[1], vh[2], vh[3]);
    *(ushort4*)(qvl + dst) = make_ushort4(vl[0], vl[1], vl[2], vl[3]);
  }
}

// ---------------- fused time attention, MFMA ----------------
// grid (P/64, C, B), block 512 (8 waves). Wave w owns logit tile rows[0..63] x cols[w*64..+63].
// 3-mfma hi/lo QK (fp32-accurate logits) -> cross-wave softmax -> head-mean in regs ->
// probs to LDS bf16 -> PV mfma with qz staged transposed per K-step.
#define T1_PSTR 1072                  // probs row stride bytes (64 rows)
#define T1_LDS_BT 68608               // 2 x [256][36] bf16 (72B rows)
#define T1_BT_BUF 18432
#define T1_LDS_REDF 105472            // [64][8] f32
#define T1_LDS_RMAX 107520            // [64] f32
#define T1_LDS_RSUM 107776            // [64] f32
#define T1_LDS_SIZE 108032

__global__ __launch_bounds__(512, 2)
void time_attn_mfma(const __hip_bfloat16* __restrict__ quh, const __hip_bfloat16* __restrict__ qul,
                    const __hip_bfloat16* __restrict__ qvh, const __hip_bfloat16* __restrict__ qvl,
                    const float* __restrict__ qz, float* __restrict__ out) {
  __shared__ char lds[T1_LDS_SIZE];
  const int b = blockIdx.z, c = blockIdx.y;
  const int p0 = blockIdx.x * 64;
  const int tid = threadIdx.x;
  const int w = tid >> 6;
  const int lane = tid & 63;
  const int g = lane >> 4;
  const int li = lane & 15;
  const int c0 = w * 64;
  const size_t bc = (size_t)b * C_ + c;
  const float* qzB = qz + bc * (size_t)(P_ * D_);

  float* redf = (float*)(lds + T1_LDS_REDF);
  float* rowmax = (float*)(lds + T1_LDS_RMAX);
  float* rowsum = (float*)(lds + T1_LDS_RSUM);

  f32x4 macc[4][4];
#pragma unroll
  for (int rt = 0; rt < 4; ++rt)
#pragma unroll
    for (int ct = 0; ct < 4; ++ct) macc[rt][ct] = f32x4{0.f, 0.f, 0.f, 0.f};

  for (int h = 0; h < H_; ++h) {
    const size_t hb = (bc * H_ + h) * (size_t)(P_ * 32);
    const __hip_bfloat16* quhB = quh + hb + (size_t)p0 * 32;
    const __hip_bfloat16* qulB = qul + hb + (size_t)p0 * 32;
    const __hip_bfloat16* qvhB = qvh + hb;
    const __hip_bfloat16* qvlB = qvl + hb;

    short8 ah[4], al[4];
#pragma unroll
    for (int rt = 0; rt < 4; ++rt) {
      int off = (rt * 16 + li) * 32 + g * 8;
      ah[rt] = *(const short8*)(quhB + off);
      al[rt] = *(const short8*)(qulB + off);
    }

    f32x4 acc[4][4];
#pragma unroll
    for (int rt = 0; rt < 4; ++rt)
#pragma unroll
      for (int ct = 0; ct < 4; ++ct) acc[rt][ct] = f32x4{0.f, 0.f, 0.f, 0.f};

#pragma unroll
    for (int ct = 0; ct < 4; ++ct) {
      int off = (c0 + ct * 16 + li) * 32 + g * 8;
      short8 bh = *(const short8*)(qvhB + off);
      short8 bl = *(const short8*)(qvlB + off);
#pragma unroll
      for (int rt = 0; rt < 4; ++rt) {
        acc[rt][ct] = __builtin_amdgcn_mfma_f32_16x16x32_bf16(ah[rt], bh, acc[rt][ct], 0, 0, 0);
        acc[rt][ct] = __builtin_amdgcn_mfma_f32_16x16x32_bf16(ah[rt], bl, acc[rt][ct], 0, 0, 0);
        acc[rt][ct] = __builtin_amdgcn_mfma_f32_16x16x32_bf16(al[rt], bh, acc[rt][ct], 0, 0, 0);
      }
    }

    // ---- row max (wave partial -> LDS -> stage2 -> broadcast) ----
#pragma unroll
    for (int rt = 0; rt < 4; ++rt)
#pragma unroll
      for (int j = 0; j < 4; ++j) {
        float m = fmaxf(fmaxf(acc[rt][0][j], acc[rt][1][j]), fmaxf(acc[rt][2][j], acc[rt][3][j]));
        m = fmaxf(m, __shfl_xor(m, 1));
        m = fmaxf(m, __shfl_xor(m, 2));
        m = fmaxf(m, __shfl_xor(m, 4));
        m = fmaxf(m, __shfl_xor(m, 8));
        if (li == 0) redf[(rt * 16 + g * 4 + j) * 8 + w] = m;
      }
    __syncthreads();
    if (tid < 64) {
      float m = redf[tid * 8];
#pragma unroll
      for (int k = 1; k < 8; ++k) m = fmaxf(m, redf[tid * 8 + k]);
      rowmax[tid] = m;
    }
    __syncthreads();
    float rst[4][4];
#pragma unroll
    for (int rt = 0; rt < 4; ++rt)
#pragma unroll
      for (int j = 0; j < 4; ++j) rst[rt][j] = rowmax[rt * 16 + g * 4 + j];

    // ---- exp + row sum ----
#pragma unroll
    for (int rt = 0; rt < 4; ++rt)
#pragma unroll
      for (int j = 0; j < 4; ++j) {
        float s = 0.f;
#pragma unroll
        for (int ct = 0; ct < 4; ++ct) {
          float p = __expf((acc[rt][ct][j] - rst[rt][j]) * SCALE);
          acc[rt][ct][j] = p;
          s += p;
        }
        s += __shfl_xor(s, 1);
        s += __shfl_xor(s, 2);
        s += __shfl_xor(s, 4);
        s += __shfl_xor(s, 8);
        if (li == 0) redf[(rt * 16 + g * 4 + j) * 8 + w] = s;
      }
    __syncthreads();
    if (tid < 64) {
      float s = 0.f;
#pragma unroll
      for (int k = 0; k < 8; ++k) s += redf[tid * 8 + k];
      rowsum[tid] = s;
    }
    __syncthreads();
#pragma unroll
    for (int rt = 0; rt < 4; ++rt)
#pragma unroll
      for (int j = 0; j < 4; ++j) {
        float wi = 0.125f / rowsum[rt * 16 + g * 4 + j];
#pragma unroll
        for (int ct = 0; ct < 4; ++ct) macc[rt][ct][j] += acc[rt][ct][j] * wi;
      }
  }

  // ---- head-mean probs -> LDS bf16 ----
#pragma unroll
  for (int rt = 0; rt < 4; ++rt)
#pragma unroll
    for (int j = 0; j < 4; ++j) {
      int row = rt * 16 + g * 4 + j;
#pragma unroll
      for (int ct = 0; ct < 4; ++ct) {
        int col = c0 + ct * 16 + li;
        *(unsigned short*)(lds + row * T1_PSTR + col * 2) = bf16bits(macc[rt][ct][j]);
      }
    }

  // ---- PV: (64 x 512) @ (512 x 256), qz staged transposed per K-step ----
  auto stageBt = [&](int ks) {
    const int dg = tid & 63, kq = tid >> 6;
    const int d0 = dg * 4;
    const float* src = qzB + (size_t)(ks * 32 + kq * 4) * D_ + d0;
    f32x4 v0 = *(const f32x4*)src;
    f32x4 v1 = *(const f32x4*)(src + D_);
    f32x4 v2 = *(const f32x4*)(src + 2 * D_);
    f32x4 v3 = *(const f32x4*)(src + 3 * D_);
    char* Bb = lds + T1_LDS_BT + (ks & 1) * T1_BT_BUF;
#pragma unroll
    for (int ccc = 0; ccc < 4; ++ccc) {
      int d = d0 + ccc;
      int kk = (kq * 4) ^ (((d >> 4) & 3) << 3);
      ushort4 pk = make_ushort4(bf16bits(v0[ccc]), bf16bits(v1[ccc]),
                                bf16bits(v2[ccc]), bf16bits(v3[ccc]));
      *(ushort4*)(Bb + d * 72 + kk * 2) = pk;
    }
  };

  stageBt(0);
  __syncthreads();

  f32x4 oacc[4][2];
#pragma unroll
  for (int rt = 0; rt < 4; ++rt)
#pragma unroll
    for (int ct = 0; ct < 2; ++ct) oacc[rt][ct] = f32x4{0.f, 0.f, 0.f, 0.f};

  for (int ks = 0; ks < 16; ++ks) {
    if (ks < 15) stageBt(ks + 1);
    short8 pa[4];
#pragma unroll
    for (int rt = 0; rt < 4; ++rt)
      pa[rt] = *(const short8*)(lds + (rt * 16 + li) * T1_PSTR + ks * 64 + g * 16);
    const char* Bb = lds + T1_LDS_BT + (ks & 1) * T1_BT_BUF;
#pragma unroll
    for (int ct = 0; ct < 2; ++ct) {
      const int dbase = w * 32 + ct * 16;
      const int swz = ((dbase >> 4) & 3) << 3;
      const char* bp = Bb + (dbase + li) * 72 + (((8 * g) ^ swz) * 2);
      s16x4 b0 = *(const s16x4*)bp;
      s16x4 b1 = *(const s16x4*)(bp + 8);
      short8 bz = __builtin_shufflevector(b0, b1, 0, 1, 2, 3, 4, 5, 6, 7);
#pragma unroll
      for (int rt = 0; rt < 4; ++rt)
        oacc[rt][ct] = __builtin_amdgcn_mfma_f32_16x16x32_bf16(pa[rt], bz, oacc[rt][ct], 0, 0, 0);
    }
    __syncthreads();
  }

  float* outB = out + bc * (size_t)(P_ * D_);
#pragma unroll
  for (int rt = 0; rt < 4; ++rt)
#pragma unroll
    for (int ct = 0; ct < 2; ++ct)
#pragma unroll
      for (int j = 0; j < 4; ++j)
        outB[(size_t)(p0 + rt * 16 + g * 4 + j) * D_ + w * 32 + ct * 16 + li] = oacc[rt][ct][j];
}

// ---------------- fused channel attention ----------------
__global__ __launch_bounds__(64)
void chan_attn_kernel(const float* __restrict__ qu, const float* __restrict__ qv,
                      const float* __restrict__ qz, float* __restrict__ out) {
  const int p = blockIdx.x, b = blockIdx.y;
  __shared__ float buf0[16][260];
  __shared__ float qvC[16][260];
  __shared__ float A_m[16][17];

  const int tid = threadIdx.x;
  const int f = tid & 15;
  const int gg = tid >> 4;

#pragma unroll
  for (int cc = 0; cc < 16; ++cc) {
    size_t off = (((size_t)b * C_ + cc) * P_ + p) * D_ + tid*4;
    *(f4*)&buf0[cc][tid*4] = *(const f4*)&qu[off];
    *(f4*)&qvC[cc][tid*4]  = *(const f4*)&qv[off];
  }
  __syncthreads();

  float am[4] = {0.f, 0.f, 0.f, 0.f};
  for (int h = 0; h < H_; ++h) {
    f4 vr[8];
#pragma unroll
    for (int i = 0; i < 8; ++i) vr[i] = *(const f4*)&qvC[f][h*32 + i*4];
    float sj[4];
#pragma unroll
    for (int j = 0; j < 4; ++j) {
      int cc = gg + 4*j;
      float ssum = 0.f;
#pragma unroll
      for (int i = 0; i < 8; ++i) {
        f4 uu = *(const f4*)&buf0[cc][h*32 + i*4];
        ssum += uu.x*vr[i].x + uu.y*vr[i].y + uu.z*vr[i].z + uu.w*vr[i].w;
      }
      sj[j] = ssum;
    }
#pragma unroll
    for (int j = 0; j < 4; ++j) {
      float mx = sj[j];
      for (int off = 8; off >= 1; off >>= 1) mx = fmaxf(mx, __shfl_xor(mx, off));
      float pv = __expf((sj[j] - mx) * SCALE);
      float sum = pv;
      for (int off = 8; off >= 1; off >>= 1) sum += __shfl_xor(sum, off);
      am[j] += pv * (0.125f / sum);
    }
  }
#pragma unroll
  for (int j = 0; j < 4; ++j) A_m[gg + 4*j][f] = am[j];
  __syncthreads();
#pragma unroll
  for (int cc = 0; cc < 16; ++cc) {
    size_t off = (((size_t)b * C_ + cc) * P_ + p) * D_ + tid*4;
    *(f4*)&buf0[cc][tid*4] = *(const f4*)&qz[off];
  }
  __syncthreads();

  f4 acc4[16];
#pragma unroll
  for (int cc = 0; cc < 16; ++cc) acc4[cc] = make_float4(0.f, 0.f, 0.f, 0.f);
#pragma unroll
  for (int ff = 0; ff < 16; ++ff) {
    f4 z = *(const f4*)&buf0[ff][tid*4];
#pragma unroll
    for (int cc = 0; cc < 16; ++cc) {
      float aa = A_m[cc][ff];
      acc4[cc].x = fmaf(aa, z.x, acc4[cc].x);
      acc4[cc].y = fmaf(aa, z.y, acc4[cc].y);
      acc4[cc].z = fmaf(aa, z.z, acc4[cc].z);
      acc4[cc].w = fmaf(aa, z.w, acc4[cc].w);
    }
  }
#pragma unroll
  for (int cc = 0; cc < 16; ++cc) {
    size_t off = (((size_t)b * C_ + cc) * P_ + p) * D_ + tid*4;
    *(f4*)&out[off] = acc4[cc];
  }
}

extern "C" void kernel_launch(void* const* d_in, const int* in_sizes, int n_in,
                              void* d_out, int out_size, void* d_ws, size_t ws_size,
                              hipStream_t stream) {
  const float* qz = (const float*)d_in[0];
  const float* tu = (const float*)d_in[1];
  const float* tv = (const float*)d_in[2];
  const float* cu = (const float*)d_in[3];
  const float* cv = (const float*)d_in[4];
  float* out_mt = (float*)d_out;
  float* out_mc = out_mt + (size_t)B_ * C_ * P_ * D_;

  const size_t NE = (size_t)B_ * C_ * P_ * D_;  // 8388608
  __hip_bfloat16* quh = (__hip_bfloat16*)d_ws;
  __hip_bfloat16* qul = quh + NE;
  __hip_bfloat16* qvh = qul + NE;
  __hip_bfloat16* qvl = qvh + NE;
  // channel branch reuses the same 67.1MB as fp32 (time branch is complete by then)
  float* quW = (float*)d_ws;
  float* qvW = quW + NE;

  dim3 pg(D_/64, (C_*P_)/128, B_);
  hipLaunchKernelGGL(proj_time_kernel, pg, dim3(256), 0, stream, qz, tu, tv, quh, qul, qvh, qvl);
  hipLaunchKernelGGL(time_attn_mfma, dim3(P_/64, C_, B_), dim3(512), 0, stream,
                     quh, qul, qvh, qvl, qz, out_mt);
  hipLaunchKernelGGL(proj_kernel, pg, dim3(256), 0, stream, qz, cu, cv, quW, qvW);
  hipLaunchKernelGGL(chan_attn_kernel, dim3(P_, B_), dim3(64), 0, stream,
                     quW, qvW, qz, out_mc);
}

// Round 3
// 301.036 us; speedup vs baseline: 3.4340x; 1.4660x over previous
//
#include <hip/hip_runtime.h>
#include <hip/hip_bf16.h>
#include <stdint.h>

#define B_ 4
#define C_ 16
#define P_ 512
#define D_ 256
#define H_ 8
#define SCALE 0.17677669529663687f  // 1/sqrt(32)
#define NE 8388608                   // B*C*P*D

typedef float4 f4;
typedef uint32_t u32;
typedef __attribute__((ext_vector_type(4))) float f32x4;
typedef __attribute__((ext_vector_type(8))) short short8;

__device__ __forceinline__ unsigned short bf16bits(float x) {
  union { __hip_bfloat16 h; unsigned short u; } cv;
  cv.h = __float2bfloat16(x);
  return cv.u;
}
__device__ __forceinline__ float bf2f(unsigned short u) {
  return __uint_as_float((u32)u << 16);
}
__device__ __forceinline__ u32 packbf2(float a, float b) {
  return ((u32)bf16bits(b) << 16) | bf16bits(a);
}

// ---------------- prep: qz -> qzh/qzl (hi/lo bf16) + qzT (bf16, [bc][d][p]) ----------------
__global__ __launch_bounds__(256)
void prep_qz(const float* __restrict__ qz, ushort* __restrict__ qzh,
             ushort* __restrict__ qzl, ushort* __restrict__ qzT) {
  const int bc = blockIdx.y;
  const int pt = blockIdx.x >> 2, dt = blockIdx.x & 3;
  const int t = threadIdx.x;
  const int row = t >> 2, cq = t & 3;
  __shared__ float T[64][65];

  const int p = pt * 64 + row;
  const int d0 = dt * 64 + cq * 16;
  const size_t base = (size_t)bc * 131072 + (size_t)p * 256 + d0;
  float v[16];
#pragma unroll
  for (int i = 0; i < 4; ++i) {
    f4 x = *(const f4*)(qz + base + i * 4);
    v[i*4+0] = x.x; v[i*4+1] = x.y; v[i*4+2] = x.z; v[i*4+3] = x.w;
  }
  ushort hs[16], ls[16];
#pragma unroll
  for (int e = 0; e < 16; ++e) {
    unsigned short hb = bf16bits(v[e]);
    hs[e] = hb;
    ls[e] = bf16bits(v[e] - bf2f(hb));
    T[cq * 16 + e][row] = v[e];
  }
  *(ushort4*)(qzh + base)     = make_ushort4(hs[0],hs[1],hs[2],hs[3]);
  *(ushort4*)(qzh + base + 4) = make_ushort4(hs[4],hs[5],hs[6],hs[7]);
  *(ushort4*)(qzh + base + 8) = make_ushort4(hs[8],hs[9],hs[10],hs[11]);
  *(ushort4*)(qzh + base +12) = make_ushort4(hs[12],hs[13],hs[14],hs[15]);
  *(ushort4*)(qzl + base)     = make_ushort4(ls[0],ls[1],ls[2],ls[3]);
  *(ushort4*)(qzl + base + 4) = make_ushort4(ls[4],ls[5],ls[6],ls[7]);
  *(ushort4*)(qzl + base + 8) = make_ushort4(ls[8],ls[9],ls[10],ls[11]);
  *(ushort4*)(qzl + base +12) = make_ushort4(ls[12],ls[13],ls[14],ls[15]);
  __syncthreads();
  // transpose out: thread -> d-row = t>>2, p-quarter = t&3
  const int drow = t >> 2, pq = t & 3;
  ushort os[16];
#pragma unroll
  for (int e = 0; e < 16; ++e) os[e] = bf16bits(T[drow][pq * 16 + e]);
  const size_t tbase = (size_t)bc * 131072 + (size_t)(dt * 64 + drow) * 512 + pt * 64 + pq * 16;
  *(ushort4*)(qzT + tbase)     = make_ushort4(os[0],os[1],os[2],os[3]);
  *(ushort4*)(qzT + tbase + 4) = make_ushort4(os[4],os[5],os[6],os[7]);
  *(ushort4*)(qzT + tbase + 8) = make_ushort4(os[8],os[9],os[10],os[11]);
  *(ushort4*)(qzT + tbase +12) = make_ushort4(os[12],os[13],os[14],os[15]);
}

// ---------------- prep: weights -> concat [br][b][512][256] hi/lo bf16, U rows pre-scaled ----------------
__global__ __launch_bounds__(256)
void prep_w(const float* __restrict__ tu, const float* __restrict__ tv,
            const float* __restrict__ cu, const float* __restrict__ cv,
            ushort* __restrict__ wh, ushort* __restrict__ wl) {
  const int e4 = blockIdx.x * 256 + threadIdx.x;
  const int idx = e4 * 4;
  const int k0 = idx & 255;
  const int n  = (idx >> 8) & 511;
  const int b  = (idx >> 17) & 3;
  const int br = idx >> 19;
  const float* src;
  float sc;
  if (br == 0) {
    if (n < 256) { src = tu + ((size_t)b * 256 + n) * 256 + k0; sc = SCALE; }
    else         { src = tv + ((size_t)b * 256 + (n - 256)) * 256 + k0; sc = 1.f; }
  } else {
    if (n < 256) { src = cu + ((size_t)b * 256 + n) * 256 + k0; sc = SCALE; }
    else         { src = cv + ((size_t)b * 256 + (n - 256)) * 256 + k0; sc = 1.f; }
  }
  f4 x = *(const f4*)src;
  float v[4] = {x.x * sc, x.y * sc, x.z * sc, x.w * sc};
  ushort hs[4], ls[4];
#pragma unroll
  for (int e = 0; e < 4; ++e) {
    unsigned short hb = bf16bits(v[e]);
    hs[e] = hb;
    ls[e] = bf16bits(v[e] - bf2f(hb));
  }
  const size_t dst = ((size_t)(br * 4 + b) * 512 + n) * 256 + k0;
  *(ushort4*)(wh + dst) = make_ushort4(hs[0], hs[1], hs[2], hs[3]);
  *(ushort4*)(wl + dst) = make_ushort4(ls[0], ls[1], ls[2], ls[3]);
}

// ---------------- proj_all: MFMA GEMM, M=8192/b, N=1024 (time 512 | chan 512), K=256, 3-mfma hi/lo ----------------
// grid (8, 64, 4), block 256 (4 waves, 2x2), tile 128x128, K-step 32, LDS double-buffered.
__global__ __launch_bounds__(256, 2)
void proj_all(const ushort* __restrict__ qzh, const ushort* __restrict__ qzl,
              const ushort* __restrict__ wh, const ushort* __restrict__ wl,
              ushort* __restrict__ quh, ushort* __restrict__ qul,
              ushort* __restrict__ qvh, ushort* __restrict__ qvl,
              float* __restrict__ qcu, float* __restrict__ qcv) {
  __shared__ char smem[65536];
  const int b = blockIdx.z;
  const int m0 = blockIdx.y * 128;
  const int nt = blockIdx.x;
  const int br = nt >> 2;
  const int n0l = (nt & 3) * 128;
  const int tid = threadIdx.x;
  const int w = tid >> 6, lane = tid & 63;
  const int g = lane >> 4, li = lane & 15;
  const int wm = w >> 1, wn = w & 1;

  f32x4 acc[4][4];
#pragma unroll
  for (int i = 0; i < 4; ++i)
#pragma unroll
    for (int j = 0; j < 4; ++j) acc[i][j] = f32x4{0.f,0.f,0.f,0.f};

  auto stage = [&](int buf, int ks) {
#pragma unroll
    for (int i = 0; i < 4; ++i) {
      int cch = i * 256 + tid;
      int row = cch >> 3, col = cch & 7;
      const ushort* s = (col < 4 ? qzh : qzl) + (size_t)(b * 8192 + m0 + row) * 256 + ks * 32 + (col & 3) * 8;
      uint4 v = *(const uint4*)s;
      *(uint4*)(smem + buf * 16384 + row * 128 + ((col * 16) ^ ((row & 7) << 4))) = v;
    }
#pragma unroll
    for (int i = 0; i < 4; ++i) {
      int cch = i * 256 + tid;
      int row = cch >> 3, col = cch & 7;
      const ushort* s = (col < 4 ? wh : wl) + ((size_t)(br * 4 + b) * 512 + n0l + row) * 256 + ks * 32 + (col & 3) * 8;
      uint4 v = *(const uint4*)s;
      *(uint4*)(smem + 32768 + buf * 16384 + row * 128 + ((col * 16) ^ ((row & 7) << 4))) = v;
    }
  };

  stage(0, 0);
  __syncthreads();
  int buf = 0;
  for (int ks = 0; ks < 8; ++ks) {
    if (ks < 7) stage(buf ^ 1, ks + 1);
    const char* Ab = smem + buf * 16384;
    const char* Bb = smem + 32768 + buf * 16384;
    const int sw = (li & 7) << 4;
    short8 ah[4], al[4];
#pragma unroll
    for (int mt = 0; mt < 4; ++mt) {
      int r = (wm * 64 + mt * 16 + li) * 128;
      ah[mt] = *(const short8*)(Ab + r + ((g * 16) ^ sw));
      al[mt] = *(const short8*)(Ab + r + ((64 + g * 16) ^ sw));
    }
#pragma unroll
    for (int nt2 = 0; nt2 < 4; ++nt2) {
      int r = (wn * 64 + nt2 * 16 + li) * 128;
      short8 bh = *(const short8*)(Bb + r + ((g * 16) ^ sw));
      short8 bl = *(const short8*)(Bb + r + ((64 + g * 16) ^ sw));
#pragma unroll
      for (int mt = 0; mt < 4; ++mt) {
        acc[mt][nt2] = __builtin_amdgcn_mfma_f32_16x16x32_bf16(ah[mt], bh, acc[mt][nt2], 0, 0, 0);
        acc[mt][nt2] = __builtin_amdgcn_mfma_f32_16x16x32_bf16(ah[mt], bl, acc[mt][nt2], 0, 0, 0);
        acc[mt][nt2] = __builtin_amdgcn_mfma_f32_16x16x32_bf16(al[mt], bh, acc[mt][nt2], 0, 0, 0);
      }
    }
    __syncthreads();
    buf ^= 1;
  }

  // epilogue
#pragma unroll
  for (int mt = 0; mt < 4; ++mt) {
#pragma unroll
    for (int nt2 = 0; nt2 < 4; ++nt2) {
      int nG = n0l + wn * 64 + nt2 * 16 + li;  // 0..511 within branch
#pragma unroll
      for (int j = 0; j < 4; ++j) {
        int m = m0 + wm * 64 + mt * 16 + g * 4 + j;
        int cc = m >> 9, p = m & 511;
        float val = acc[mt][nt2][j];
        if (br == 0) {
          int nn = nG & 255;
          int h = nn >> 5, r = nn & 31;
          size_t dst = ((((size_t)b * 16 + cc) * 8 + h) * 512 + p) * 32 + r;
          unsigned short hb = bf16bits(val);
          unsigned short lb = bf16bits(val - bf2f(hb));
          if (nG < 256) { quh[dst] = hb; qul[dst] = lb; }
          else          { qvh[dst] = hb; qvl[dst] = lb; }
        } else {
          size_t dst = ((size_t)(b * 16 + cc) * 512 + p) * 256 + (nG & 255);
          if (nG < 256) qcu[dst] = val;
          else          qcv[dst] = val;
        }
      }
    }
  }
}

// ---------------- fused time attention v2 ----------------
// grid (8, 16, 4), block 256 (4 waves). Wave w owns queries [p0+w*16, +16) x all 512 keys.
// Swapped QK (S^T = qv @ qu^T) -> wave-local online softmax (2 shfl) -> head-mean in regs.
// K staged per head in LDS (128B rows, hi|lo, XOR (key&7)<<4). Then probs->LDS bf16, PV mfma.
__global__ __launch_bounds__(256, 2)
void time_attn_v2(const ushort* __restrict__ quh, const ushort* __restrict__ qul,
                  const ushort* __restrict__ qvh, const ushort* __restrict__ qvl,
                  const ushort* __restrict__ qzT, float* __restrict__ out) {
  __shared__ char lds[65536];
  const int p0 = blockIdx.x * 64;
  const int bc = blockIdx.z * 16 + blockIdx.y;
  const int tid = threadIdx.x;
  const int w = tid >> 6, lane = tid & 63;
  const int g = lane >> 4, li = lane & 15;
  const int sw = (li & 7) << 4;

  f32x4 macc[32];
#pragma unroll
  for (int kt = 0; kt < 32; ++kt) macc[kt] = f32x4{0.f,0.f,0.f,0.f};

  for (int h = 0; h < H_; ++h) {
    __syncthreads();
    const size_t hb = (size_t)bc * 131072 + h * 16384;
    const ushort* qvhH = qvh + hb;
    const ushort* qvlH = qvl + hb;
    // stage all 512 keys: [key][hi 64B | lo 64B], XOR swizzle
#pragma unroll
    for (int i = 0; i < 16; ++i) {
      int cch = i * 256 + tid;
      int key = cch >> 3, col = cch & 7;
      const ushort* s = (col < 4 ? qvhH : qvlH) + key * 32 + (col & 3) * 8;
      uint4 v = *(const uint4*)s;
      *(uint4*)(lds + key * 128 + ((col * 16) ^ ((key & 7) << 4))) = v;
    }
    // B-frags: this wave's 16 queries
    const size_t qoff = hb + (size_t)(p0 + w * 16 + li) * 32 + g * 8;
    short8 bh = *(const short8*)(quh + qoff);
    short8 bl = *(const short8*)(qul + qoff);
    __syncthreads();

    float m = -3.402823e38f, l = 0.f;
#pragma unroll 4
    for (int kt = 0; kt < 32; ++kt) {
      const char* rp = lds + (kt * 16 + li) * 128;
      short8 a_h = *(const short8*)(rp + ((g * 16) ^ sw));
      short8 a_l = *(const short8*)(rp + ((64 + g * 16) ^ sw));
      f32x4 t = f32x4{0.f,0.f,0.f,0.f};
      t = __builtin_amdgcn_mfma_f32_16x16x32_bf16(a_h, bh, t, 0, 0, 0);
      t = __builtin_amdgcn_mfma_f32_16x16x32_bf16(a_h, bl, t, 0, 0, 0);
      t = __builtin_amdgcn_mfma_f32_16x16x32_bf16(a_l, bh, t, 0, 0, 0);
      float tm = fmaxf(fmaxf(t[0], t[1]), fmaxf(t[2], t[3]));
      tm = fmaxf(tm, __shfl_xor(tm, 16));
      tm = fmaxf(tm, __shfl_xor(tm, 32));
      float mn = fmaxf(m, tm);
      float ts = __expf(t[0] - mn) + __expf(t[1] - mn) + __expf(t[2] - mn) + __expf(t[3] - mn);
      ts += __shfl_xor(ts, 16);
      ts += __shfl_xor(ts, 32);
      l = l * __expf(m - mn) + ts;
      m = mn;
    }
    float rinv = 0.125f / l;
#pragma unroll
    for (int kt = 0; kt < 32; ++kt) {
      const char* rp = lds + (kt * 16 + li) * 128;
      short8 a_h = *(const short8*)(rp + ((g * 16) ^ sw));
      short8 a_l = *(const short8*)(rp + ((64 + g * 16) ^ sw));
      f32x4 t = f32x4{0.f,0.f,0.f,0.f};
      t = __builtin_amdgcn_mfma_f32_16x16x32_bf16(a_h, bh, t, 0, 0, 0);
      t = __builtin_amdgcn_mfma_f32_16x16x32_bf16(a_h, bl, t, 0, 0, 0);
      t = __builtin_amdgcn_mfma_f32_16x16x32_bf16(a_l, bh, t, 0, 0, 0);
#pragma unroll
      for (int j = 0; j < 4; ++j)
        macc[kt][j] += __expf(t[j] - m) * rinv;
    }
  }

  // head-mean probs -> LDS (transposed to [q_local][key], bf16, XOR swizzle on 1024B rows)
  __syncthreads();
  {
    const int q_l = w * 16 + li;
#pragma unroll
    for (int kt = 0; kt < 32; ++kt) {
      u32 u0 = packbf2(macc[kt][0], macc[kt][1]);
      u32 u1 = packbf2(macc[kt][2], macc[kt][3]);
      *(uint2*)(lds + q_l * 1024 + ((kt * 32 + g * 8) ^ sw)) = make_uint2(u0, u1);
    }
  }
  __syncthreads();

  // PV: out[q][d] = probs[q][:] @ qzT[d][:]^T
  f32x4 oacc[16];
#pragma unroll
  for (int dt = 0; dt < 16; ++dt) oacc[dt] = f32x4{0.f,0.f,0.f,0.f};
  const ushort* qzTb = qzT + (size_t)bc * 131072;
#pragma unroll 2
  for (int ks = 0; ks < 16; ++ks) {
    short8 pa = *(const short8*)(lds + (w * 16 + li) * 1024 + ((ks * 64 + g * 16) ^ sw));
#pragma unroll
    for (int dt = 0; dt < 16; ++dt) {
      short8 bz = *(const short8*)(qzTb + (size_t)(dt * 16 + li) * 512 + ks * 32 + g * 8);
      oacc[dt] = __builtin_amdgcn_mfma_f32_16x16x32_bf16(pa, bz, oacc[dt], 0, 0, 0);
    }
  }
  float* outB = out + (size_t)bc * 131072;
#pragma unroll
  for (int dt = 0; dt < 16; ++dt)
#pragma unroll
    for (int j = 0; j < 4; ++j)
      outB[(size_t)(p0 + w * 16 + g * 4 + j) * 256 + dt * 16 + li] = oacc[dt][j];
}

// ---------------- fused channel attention (inputs pre-scaled; qu/qv live in d_out regions) ----------------
__global__ __launch_bounds__(64)
void chan_attn_kernel(const float* __restrict__ qu, const float* __restrict__ qv,
                      const float* __restrict__ qz, float* __restrict__ out) {
  const int p = blockIdx.x, b = blockIdx.y;
  __shared__ float buf0[16][260];
  __shared__ float qvC[16][260];
  __shared__ float A_m[16][17];

  const int tid = threadIdx.x;
  const int f = tid & 15;
  const int gg = tid >> 4;

#pragma unroll
  for (int cc = 0; cc < 16; ++cc) {
    size_t off = (((size_t)b * C_ + cc) * P_ + p) * D_ + tid*4;
    *(f4*)&buf0[cc][tid*4] = *(const f4*)&qu[off];
    *(f4*)&qvC[cc][tid*4]  = *(const f4*)&qv[off];
  }
  __syncthreads();

  float am[4] = {0.f, 0.f, 0.f, 0.f};
  for (int h = 0; h < H_; ++h) {
    f4 vr[8];
#pragma unroll
    for (int i = 0; i < 8; ++i) vr[i] = *(const f4*)&qvC[f][h*32 + i*4];
    float sj[4];
#pragma unroll
    for (int j = 0; j < 4; ++j) {
      int cc = gg + 4*j;
      float ssum = 0.f;
#pragma unroll
      for (int i = 0; i < 8; ++i) {
        f4 uu = *(const f4*)&buf0[cc][h*32 + i*4];
        ssum += uu.x*vr[i].x + uu.y*vr[i].y + uu.z*vr[i].z + uu.w*vr[i].w;
      }
      sj[j] = ssum;
    }
#pragma unroll
    for (int j = 0; j < 4; ++j) {
      float mx = sj[j];
      for (int off = 8; off >= 1; off >>= 1) mx = fmaxf(mx, __shfl_xor(mx, off));
      float pv = __expf(sj[j] - mx);
      float sum = pv;
      for (int off = 8; off >= 1; off >>= 1) sum += __shfl_xor(sum, off);
      am[j] += pv * (0.125f / sum);
    }
  }
#pragma unroll
  for (int j = 0; j < 4; ++j) A_m[gg + 4*j][f] = am[j];
  __syncthreads();
#pragma unroll
  for (int cc = 0; cc < 16; ++cc) {
    size_t off = (((size_t)b * C_ + cc) * P_ + p) * D_ + tid*4;
    *(f4*)&buf0[cc][tid*4] = *(const f4*)&qz[off];
  }
  __syncthreads();

  f4 acc4[16];
#pragma unroll
  for (int cc = 0; cc < 16; ++cc) acc4[cc] = make_float4(0.f, 0.f, 0.f, 0.f);
#pragma unroll
  for (int ff = 0; ff < 16; ++ff) {
    f4 z = *(const f4*)&buf0[ff][tid*4];
#pragma unroll
    for (int cc = 0; cc < 16; ++cc) {
      float aa = A_m[cc][ff];
      acc4[cc].x = fmaf(aa, z.x, acc4[cc].x);
      acc4[cc].y = fmaf(aa, z.y, acc4[cc].y);
      acc4[cc].z = fmaf(aa, z.z, acc4[cc].z);
      acc4[cc].w = fmaf(aa, z.w, acc4[cc].w);
    }
  }
#pragma unroll
  for (int cc = 0; cc < 16; ++cc) {
    size_t off = (((size_t)b * C_ + cc) * P_ + p) * D_ + tid*4;
    *(f4*)&out[off] = acc4[cc];
  }
}

extern "C" void kernel_launch(void* const* d_in, const int* in_sizes, int n_in,
                              void* d_out, int out_size, void* d_ws, size_t ws_size,
                              hipStream_t stream) {
  const float* qz = (const float*)d_in[0];
  const float* tu = (const float*)d_in[1];
  const float* tv = (const float*)d_in[2];
  const float* cu = (const float*)d_in[3];
  const float* cv = (const float*)d_in[4];
  float* out_mt = (float*)d_out;
  float* out_mc = out_mt + (size_t)NE;

  ushort* W = (ushort*)d_ws;
  ushort* qzh = W;
  ushort* qzl = qzh + NE;
  ushort* qzT = qzl + NE;
  ushort* wh  = qzT + NE;
  ushort* wl  = wh + 1048576;
  ushort* quh = wl + 1048576;
  ushort* qul = quh + NE;
  ushort* qvh = qul + NE;
  ushort* qvl = qvh + NE;
  // channel qu/qv scratch lives in d_out (qu_c in out_mt, qv_c in out_mc):
  // proj_all -> chan_attn (reads both, rewrites out_mc cells it read) -> time_attn_v2 (overwrites out_mt)
  float* qcu = out_mt;
  float* qcv = out_mc;

  hipLaunchKernelGGL(prep_qz, dim3(32, 64), dim3(256), 0, stream, qz, qzh, qzl, qzT);
  hipLaunchKernelGGL(prep_w, dim3(1024), dim3(256), 0, stream, tu, tv, cu, cv, wh, wl);
  hipLaunchKernelGGL(proj_all, dim3(8, 64, 4), dim3(256), 0, stream,
                     qzh, qzl, wh, wl, quh, qul, qvh, qvl, qcu, qcv);
  hipLaunchKernelGGL(chan_attn_kernel, dim3(P_, B_), dim3(64), 0, stream,
                     qcu, qcv, qz, out_mc);
  hipLaunchKernelGGL(time_attn_v2, dim3(8, 16, 4), dim3(256), 0, stream,
                     quh, qul, qvh, qvl, qzT, out_mt);
}